// Round 8
// baseline (240.261 us; speedup 1.0000x reference)
//
#include <hip/hip_runtime.h>

#define DD 256
#define NGRAPH 64
#define NCLS 60
#define BN_EPS 1e-5f
#define SCAN_B 256
#define NSLICE 8
#define NCHUNK 256
#define AGG_BLOCKS (NSLICE * NCHUNK)  // 2048

typedef __attribute__((ext_vector_type(8))) short bf16x8;
typedef __attribute__((ext_vector_type(4))) float f32x4;

__device__ __forceinline__ unsigned short f2bf(float f) {
    union { float f; unsigned u; } v;
    v.f = f;
    unsigned r = v.u + 0x7FFFu + ((v.u >> 16) & 1u);  // RNE
    return (unsigned short)(r >> 16);
}
__device__ __forceinline__ float bf2f(unsigned short u) {
    union { unsigned u; float f; } v;
    v.u = ((unsigned)u) << 16;
    return v.f;
}

// ---------------- degree ----------------
__global__ void k_degcount(const int* __restrict__ dst, int E, int* __restrict__ degcnt) {
    int e = blockIdx.x * blockDim.x + threadIdx.x;
    if (e < E) atomicAdd(&degcnt[dst[e]], 1);
}

// ---------------- per-graph node counts via binary search (batch sorted) ----------------
__global__ void k_gcount(const int* __restrict__ batch, int N, int* __restrict__ cnt) {
    int g = threadIdx.x;
    if (g >= NGRAPH) return;
    int lo = 0, hi = N;
    while (lo < hi) { int mid = (lo + hi) >> 1; if (batch[mid] < g) lo = mid + 1; else hi = mid; }
    int start = lo;
    lo = 0; hi = N;
    while (lo < hi) { int mid = (lo + hi) >> 1; if (batch[mid] < g + 1) lo = mid + 1; else hi = mid; }
    cnt[g] = lo - start;
}

// ---------------- exclusive scan (3-phase) for CSR rowptr ----------------
__global__ void k_scan1(const int* __restrict__ in, int n, int* __restrict__ out,
                        int* __restrict__ bsum) {
    __shared__ int sm[SCAN_B];
    int i = blockIdx.x * SCAN_B + threadIdx.x;
    int v = (i < n) ? in[i] : 0;
    sm[threadIdx.x] = v;
    __syncthreads();
    int acc = v;
    for (int off = 1; off < SCAN_B; off <<= 1) {
        int t = (threadIdx.x >= off) ? sm[threadIdx.x - off] : 0;
        __syncthreads();
        acc += t;
        sm[threadIdx.x] = acc;
        __syncthreads();
    }
    if (i < n) out[i] = acc - v;
    if (threadIdx.x == SCAN_B - 1) bsum[blockIdx.x] = acc;
}

__global__ void k_scan2(int* __restrict__ bsum, int nb, int* __restrict__ total) {
    __shared__ int sm[SCAN_B];
    __shared__ int carry;
    if (threadIdx.x == 0) carry = 0;
    __syncthreads();
    for (int base = 0; base < nb; base += SCAN_B) {
        int i = base + threadIdx.x;
        int v = (i < nb) ? bsum[i] : 0;
        sm[threadIdx.x] = v;
        __syncthreads();
        int acc = v;
        for (int off = 1; off < SCAN_B; off <<= 1) {
            int t = (threadIdx.x >= off) ? sm[threadIdx.x - off] : 0;
            __syncthreads();
            acc += t;
            sm[threadIdx.x] = acc;
            __syncthreads();
        }
        if (i < nb) bsum[i] = carry + acc - v;
        __syncthreads();
        if (threadIdx.x == SCAN_B - 1) carry += acc;
        __syncthreads();
    }
    if (threadIdx.x == 0 && total) *total = carry;
}

__global__ void k_scan3(int* __restrict__ out, int n, const int* __restrict__ bsum) {
    int i = blockIdx.x * SCAN_B + threadIdx.x;
    if (i < n) out[i] += bsum[blockIdx.x];
}

// ---------------- CSR bucket fill: packed 4B (src:16 | norm_bf16:16) ----------------
__global__ void k_fill(const int* __restrict__ src, const int* __restrict__ dst,
                       const int* __restrict__ degcnt, const int* __restrict__ rowptr,
                       int* __restrict__ fill, int E, unsigned* __restrict__ esw) {
    int e = blockIdx.x * blockDim.x + threadIdx.x;
    if (e >= E) return;
    int s = src[e], d = dst[e];
    float w = rsqrtf((float)(degcnt[s] + 1)) * rsqrtf((float)(degcnt[d] + 1));
    int pos = atomicAdd(&fill[d], 1);
    int slot = rowptr[d] + pos;
    esw[slot] = (unsigned)s | ((unsigned)f2bf(w) << 16);  // N < 65536
}

// ---------------- W transpose+convert (once): Wt[n][k] bf16 = W[k][n] f32 ----------------
__global__ void k_wt(const float* __restrict__ W, unsigned short* __restrict__ Wt) {
    int n = blockIdx.x;
    int k = threadIdx.x;
    Wt[n * DD + k] = f2bf(W[k * DD + n]);
}

// ---------------- MFMA GEMM: 128x256 tile (full width), 512 threads ----------------
#define GBM 128
#define GBN 256
__global__ __launch_bounds__(512) void k_gemm_mfma(const float* __restrict__ A,
                                                   const unsigned short* __restrict__ Wtg,
                                                   unsigned short* __restrict__ C, int M) {
    __shared__ short Wt[GBN * 256];  // full weight [n][k] bf16, XOR-swizzled, 128 KB
    __shared__ short At[GBM * 32];   // [row][k] bf16 per k-step, swizzled, 8 KB
    const int tid = threadIdx.x;
    const int wave = tid >> 6;        // 0..7
    const int lane = tid & 63;
    const int row0 = blockIdx.x * GBM;

    // ---- stage Wt: 8192 chunks of 16B, 16 per thread
#pragma unroll
    for (int i = 0; i < 16; ++i) {
        int cid = tid + i * 512;
        int n = cid >> 5;
        int k0 = (cid & 31) * 8;
        bf16x8 pk = *(const bf16x8*)&Wtg[(size_t)n * DD + k0];
        int byte = (n * 512 + k0 * 2) ^ ((n & 7) << 4);
        *(bf16x8*)((char*)Wt + byte) = pk;
    }

    f32x4 acc[16];
#pragma unroll
    for (int j = 0; j < 16; ++j) acc[j] = (f32x4){0.f, 0.f, 0.f, 0.f};

    const int arow = tid >> 2;        // 0..127
    const int aslot = tid & 3;        // 0..3 (8 k's each)
    const int grow = row0 + arow;
    const int frow = wave * 16 + (lane & 15);   // 0..127
    const int g = lane >> 4;
    const int abyte_st = (arow * 64 + aslot * 16) ^ ((arow & 3) << 4);
    const float* ap = (grow < M) ? &A[(size_t)grow * DD + aslot * 8] : nullptr;

    float4 va = make_float4(0.f, 0.f, 0.f, 0.f);
    float4 vb = make_float4(0.f, 0.f, 0.f, 0.f);
    if (ap) { va = *(const float4*)ap; vb = *(const float4*)(ap + 4); }

    for (int kb = 0; kb < DD; kb += 32) {
        __syncthreads();
        {
            bf16x8 pk;
            pk[0] = (short)f2bf(va.x); pk[1] = (short)f2bf(va.y);
            pk[2] = (short)f2bf(va.z); pk[3] = (short)f2bf(va.w);
            pk[4] = (short)f2bf(vb.x); pk[5] = (short)f2bf(vb.y);
            pk[6] = (short)f2bf(vb.z); pk[7] = (short)f2bf(vb.w);
            *(bf16x8*)((char*)At + abyte_st) = pk;
        }
        __syncthreads();

        if (kb + 32 < DD && ap) {
            va = *(const float4*)(ap + kb + 32);
            vb = *(const float4*)(ap + kb + 36);
        }

        int abyte = (frow * 64 + g * 16) ^ ((frow & 3) << 4);
        bf16x8 af = *(const bf16x8*)((const char*)At + abyte);
#pragma unroll
        for (int j = 0; j < 16; ++j) {
            int n = j * 16 + (lane & 15);
            int bbyte = (n * 512 + (kb + g * 8) * 2) ^ ((n & 7) << 4);
            bf16x8 bfr = *(const bf16x8*)((const char*)Wt + bbyte);
            acc[j] = __builtin_amdgcn_mfma_f32_16x16x32_bf16(af, bfr, acc[j], 0, 0, 0);
        }
    }

#pragma unroll
    for (int j = 0; j < 16; ++j) {
        int col = j * 16 + (lane & 15);
#pragma unroll
        for (int r = 0; r < 4; ++r) {
            int row = row0 + wave * 16 + g * 4 + r;
            if (row < M) C[(size_t)row * DD + col] = f2bf(acc[j][r]);
        }
    }
}

// ---------------- column-sliced pull aggregation: slice = blockIdx&7 -> XCD-local L2 ----------------
// Each 16-lane group owns one node; lane reads 2 bf16 cols (ushort2, 64B/group/edge).
__global__ __launch_bounds__(256) void k_aggpull(const unsigned short* __restrict__ xwb,
                                                 const int* __restrict__ rowptr,
                                                 const unsigned* __restrict__ esw,
                                                 const int* __restrict__ degcnt,
                                                 const float* __restrict__ b,
                                                 unsigned short* __restrict__ aggb,
                                                 float* __restrict__ ps,
                                                 float* __restrict__ ps2, int N) {
    __shared__ float sred[256 * 2];
    __shared__ float qred[256 * 2];
    const int tid = threadIdx.x;
    const int slice = blockIdx.x & (NSLICE - 1);
    const int chunk = blockIdx.x >> 3;
    const int grp = tid >> 4;          // 0..15
    const int lg = tid & 15;
    const int col = slice * 32 + lg * 2;

    const int npc = (N + NCHUNK - 1) / NCHUNK;
    const int n0 = chunk * npc;
    const int n1 = min(N, n0 + npc);

    const float b0 = b[col], b1 = b[col + 1];
    float s0 = 0.f, s1 = 0.f, q0 = 0.f, q1 = 0.f;

    for (int n = n0 + grp; n < n1; n += 16) {
        float di = rsqrtf((float)(degcnt[n] + 1));
        float w0 = di * di;
        ushort2 v = *(const ushort2*)&xwb[(size_t)n * DD + col];
        float a0 = bf2f(v.x) * w0;
        float a1 = bf2f(v.y) * w0;

        int j0 = rowptr[n], j1 = rowptr[n + 1];
        int j = j0;
        for (; j + 7 < j1; j += 8) {
            unsigned e[8];
            ushort2 u[8];
#pragma unroll
            for (int t = 0; t < 8; ++t) e[t] = esw[j + t];
#pragma unroll
            for (int t = 0; t < 8; ++t)
                u[t] = *(const ushort2*)&xwb[(size_t)(e[t] & 0xFFFFu) * DD + col];
#pragma unroll
            for (int t = 0; t < 8; ++t) {
                float w = bf2f((unsigned short)(e[t] >> 16));
                a0 += bf2f(u[t].x) * w;
                a1 += bf2f(u[t].y) * w;
            }
        }
        for (; j + 1 < j1; j += 2) {
            unsigned ea = esw[j], eb = esw[j + 1];
            ushort2 ua = *(const ushort2*)&xwb[(size_t)(ea & 0xFFFFu) * DD + col];
            ushort2 ub = *(const ushort2*)&xwb[(size_t)(eb & 0xFFFFu) * DD + col];
            float wa = bf2f((unsigned short)(ea >> 16));
            float wb = bf2f((unsigned short)(eb >> 16));
            a0 += bf2f(ua.x) * wa + bf2f(ub.x) * wb;
            a1 += bf2f(ua.y) * wa + bf2f(ub.y) * wb;
        }
        if (j < j1) {
            unsigned ea = esw[j];
            ushort2 ua = *(const ushort2*)&xwb[(size_t)(ea & 0xFFFFu) * DD + col];
            float wa = bf2f((unsigned short)(ea >> 16));
            a0 += bf2f(ua.x) * wa;
            a1 += bf2f(ua.y) * wa;
        }
        a0 += b0;
        a1 += b1;

        ushort2 o;
        o.x = f2bf(a0);
        o.y = f2bf(a1);
        *(ushort2*)&aggb[(size_t)n * DD + col] = o;

        s0 += a0; q0 += a0 * a0;
        s1 += a1; q1 += a1 * a1;
    }

    // block-reduce: 16 groups alias the same 32 columns
    sred[tid * 2] = s0; sred[tid * 2 + 1] = s1;
    qred[tid * 2] = q0; qred[tid * 2 + 1] = q1;
    __syncthreads();
    if (tid < 32) {
        float s = 0.f, q = 0.f;
#pragma unroll
        for (int g2 = 0; g2 < 16; ++g2) {
            int idx = (g2 * 16 + (tid >> 1)) * 2 + (tid & 1);
            s += sred[idx];
            q += qred[idx];
        }
        ps[(size_t)blockIdx.x * 32 + tid] = s;
        ps2[(size_t)blockIdx.x * 32 + tid] = q;
    }
}

// ---------------- reduce per-block partials -> colsum/colsumsq ----------------
__global__ __launch_bounds__(256) void k_bnred(const float* __restrict__ ps,
                                               const float* __restrict__ ps2,
                                               float* __restrict__ colsum,
                                               float* __restrict__ colsumsq) {
    int d = threadIdx.x;               // global column
    int slice = d >> 5, t = d & 31;
    int c0 = blockIdx.x * (NCHUNK / gridDim.x);
    int c1 = c0 + (NCHUNK / gridDim.x);
    float s = 0.f, q = 0.f;
    for (int c = c0; c < c1; ++c) {
        size_t idx = ((size_t)(c * NSLICE + slice)) * 32 + t;
        s += ps[idx];
        q += ps2[idx];
    }
    atomicAdd(&colsum[d], s);
    atomicAdd(&colsumsq[d], q);
}

// ---------------- BN-apply + ReLU + per-graph pooled sums ----------------
__global__ __launch_bounds__(256) void k_pool(const unsigned short* __restrict__ aggb,
                                              const int* __restrict__ batch,
                                              const float* __restrict__ colsum,
                                              const float* __restrict__ colsumsq,
                                              const float* __restrict__ gamma,
                                              const float* __restrict__ beta,
                                              float* __restrict__ pooledsum, int N) {
    int d = threadIdx.x;
    float m = colsum[d] / (float)N;
    float var = colsumsq[d] / (float)N - m * m;
    float rs = rsqrtf(var + BN_EPS);
    float g = gamma[d], bt = beta[d];
    int rows_per = (N + gridDim.x - 1) / gridDim.x;
    int n0 = blockIdx.x * rows_per;
    int n1 = min(N, n0 + rows_per);
    if (n0 >= N) return;
    int cur = batch[n0];
    float acc = 0.f;
    for (int n = n0; n < n1; ++n) {
        int bg = batch[n];
        if (bg != cur) {
            atomicAdd(&pooledsum[cur * DD + d], acc);
            acc = 0.f;
            cur = bg;
        }
        float a = bf2f(aggb[(size_t)n * DD + d]);
        float h = g * (a - m) * rs + bt;
        acc += fmaxf(h, 0.f);
    }
    atomicAdd(&pooledsum[cur * DD + d], acc);
}

// ---------------- head: mean-pool finalize + FC + log_softmax ----------------
__global__ void k_head(const float* __restrict__ pooledsum, const int* __restrict__ cnt,
                       const float* __restrict__ Wf, const float* __restrict__ bfv,
                       float* __restrict__ out) {
    int g = blockIdx.x;
    int lane = threadIdx.x;
    __shared__ float pm[DD];
    float c = fmaxf((float)cnt[g], 1.0f);
    for (int k = lane; k < DD; k += 64) pm[k] = pooledsum[g * DD + k] / c;
    __syncthreads();
    float logit = -INFINITY;
    if (lane < NCLS) {
        float s = bfv[lane];
        for (int k = 0; k < DD; ++k) s += pm[k] * Wf[lane * DD + k];
        logit = s;
    }
    float mx = logit;
#pragma unroll
    for (int off = 32; off; off >>= 1) mx = fmaxf(mx, __shfl_xor(mx, off));
    float ex = (lane < NCLS) ? expf(logit - mx) : 0.f;
    float sum = ex;
#pragma unroll
    for (int off = 32; off; off >>= 1) sum += __shfl_xor(sum, off);
    if (lane < NCLS) out[g * NCLS + lane] = logit - mx - logf(sum);
}

extern "C" void kernel_launch(void* const* d_in, const int* in_sizes, int n_in,
                              void* d_out, int out_size, void* d_ws, size_t ws_size,
                              hipStream_t stream) {
    const float* x     = (const float*)d_in[0];
    const int*   ei    = (const int*)d_in[1];
    const int*   batch = (const int*)d_in[2];
    const float* W     = (const float*)d_in[3];
    const float* b     = (const float*)d_in[4];
    const float* gamma = (const float*)d_in[5];
    const float* beta  = (const float*)d_in[6];
    const float* Wf    = (const float*)d_in[7];
    const float* bf    = (const float*)d_in[8];
    float* out = (float*)d_out;

    const int E = in_sizes[1] / 2;
    const int N = in_sizes[2];
    const int* src = ei;
    const int* dst = ei + E;

    size_t off = 0;
    auto alloc = [&](size_t bytes) {
        void* p = (char*)d_ws + off;
        off += (bytes + 255) & ~(size_t)255;
        return p;
    };
    // --- zero-init region (contiguous, single memset) ---
    char* zbase = (char*)d_ws;
    int*   degcnt    = (int*)alloc((size_t)N * 4);
    int*   fillc     = (int*)alloc((size_t)N * 4);
    float* colsum    = (float*)alloc(DD * 4);
    float* colsumsq  = (float*)alloc(DD * 4);
    float* pooledsum = (float*)alloc(NGRAPH * DD * 4);
    size_t zbytes = off;
    // --- rest (written before read every call) ---
    unsigned short* xwb  = (unsigned short*)alloc((size_t)N * DD * 2);
    unsigned short* aggb = (unsigned short*)alloc((size_t)N * DD * 2);
    unsigned short* wtg  = (unsigned short*)alloc((size_t)DD * DD * 2);
    float* ps        = (float*)alloc((size_t)AGG_BLOCKS * 32 * 4);
    float* ps2       = (float*)alloc((size_t)AGG_BLOCKS * 32 * 4);
    int*   rowptr    = (int*)alloc(((size_t)N + 1) * 4);
    unsigned* esw    = (unsigned*)alloc((size_t)E * 4);
    int*   bsum      = (int*)alloc(((size_t)N / SCAN_B + 2) * 4);
    int*   cnt       = (int*)alloc(NGRAPH * 4);

    hipMemsetAsync(zbase, 0, zbytes, stream);

    k_degcount<<<(E + 255) / 256, 256, 0, stream>>>(dst, E, degcnt);
    k_gcount<<<1, 64, 0, stream>>>(batch, N, cnt);

    int nblk = (N + SCAN_B - 1) / SCAN_B;
    k_scan1<<<nblk, SCAN_B, 0, stream>>>(degcnt, N, rowptr, bsum);
    k_scan2<<<1, SCAN_B, 0, stream>>>(bsum, nblk, &rowptr[N]);
    k_scan3<<<nblk, SCAN_B, 0, stream>>>(rowptr, N, bsum);
    k_fill<<<(E + 255) / 256, 256, 0, stream>>>(src, dst, degcnt, rowptr, fillc, E, esw);

    k_wt<<<DD, DD, 0, stream>>>(W, wtg);
    k_gemm_mfma<<<(N + GBM - 1) / GBM, 512, 0, stream>>>(x, wtg, xwb, N);

    k_aggpull<<<AGG_BLOCKS, 256, 0, stream>>>(xwb, rowptr, esw, degcnt, b, aggb, ps, ps2, N);

    k_bnred<<<64, 256, 0, stream>>>(ps, ps2, colsum, colsumsq);
    k_pool<<<1024, 256, 0, stream>>>(aggb, batch, colsum, colsumsq, gamma, beta, pooledsum, N);
    k_head<<<NGRAPH, 64, 0, stream>>>(pooledsum, cnt, Wf, bf, out);
}